// Round 8
// baseline (155.448 us; speedup 1.0000x reference)
//
#include <hip/hip_runtime.h>

// LIF neuron bank: B=16, N=2048, T=1000. Sequential scan in T per neuron.
//
// R7: 4 mega-phases (256 steps), 8 barriers total, 1KB contiguous stores.
//   wave 0 (compute): R4's proven register-prefetched u loads (16 float4
//     groups, A/B alternation), serial LIF chain, v -> LDS (padded rows,
//     bank-floor writes), spikes -> bit-pack (2 u32 / 64 steps, off-chain).
//   waves 1,2 (v-storers): after B1 register-stage 32 rows x ds_read_b128
//     (128 VGPRs), signal B2 (buffer free), then store: ONE INSTRUCTION =
//     ONE ROW's full 256-step window = 1024B contiguous (DRAM-page sized,
//     the fillBuffer pattern). Stores drain during next compute phase.
//   wave 3 (s-storer): expands double-buffered bit-pack -> exact 1.0f/0.0f,
//     same 1KB-per-instruction store pattern (no LDS hold: bits dbuf'd).
// LDS: v 64x260 floats (66.5KB, +1-word pad -> uniform bank floor) + bits
// 4KB = 70.7KB -> 2 blocks/CU, 8 waves/CU. Barriers are raw s_barrier
// (LDS-ordering only); global stores NEVER drained in-loop.
// Steps 1000..1023 computed with u=0 and never stored (uniform phases).
//
// FP discipline: reference does NOT contract mul+add into FMA; use
// __fmul_rn/__fadd_rn/__fsub_rn to stay bit-exact (R0-R6: absmax 0.0).

constexpr int B_ = 16;
constexpr int N_ = 2048;
constexpr int T_ = 1000;
constexpr int QSTEP = 256;            // steps per phase
constexpr int NPH = 4;                // phases (last stores only 232 steps)
constexpr int ROWW = 260;             // padded row width in floats (65 f4)

#define WAVE_BARRIER()                                         \
    do {                                                       \
        __builtin_amdgcn_s_barrier();                          \
        __builtin_amdgcn_sched_barrier(0);                     \
    } while (0)
#define LGKM0()                                                \
    do {                                                       \
        asm volatile("s_waitcnt lgkmcnt(0)" ::: "memory");     \
        __builtin_amdgcn_sched_barrier(0);                     \
    } while (0)

__global__ __launch_bounds__(256) void lif_kernel(
    const float* __restrict__ u,          // (B, N, T)
    const float* __restrict__ theta_base, // (1, N, 1) -> N floats
    float* __restrict__ spikes,           // (B, N, T)
    float* __restrict__ vhist)            // (B, N, T)
{
    __shared__ float v_lds[64][ROWW];        // 66,560 B, single buffer
    __shared__ unsigned s_bits[2][64][8];    //  4,096 B, double buffer

    const int lane = threadIdx.x & 63;
    const int wid = threadIdx.x >> 6;
    const int blk0 = blockIdx.x * 64;        // first neuron of block

    if (wid == 0) {
        // ---------------- compute wave ----------------
        const float tb = theta_base[(blk0 + lane) & (N_ - 1)];
        const float c5 = __fmul_rn(tb, 0.005f);   // tb * (1-0.995) rounded
        float v = 0.0f, theta = tb, ref = 0.0f;
        const float* up = u + (size_t)(blk0 + lane) * T_;

        float4 bufA[16], bufB[16];   // named bufs: static indexing only

        // load u group gi (64 steps = 16 float4); gi==15 is 10 real + 6 zero
        auto load_g = [&](float4 (&b)[16], int gi) {
            if (gi < 15) {
#pragma unroll
                for (int i = 0; i < 16; ++i)
                    b[i] = *reinterpret_cast<const float4*>(up + 64 * gi + 4 * i);
            } else {
#pragma unroll
                for (int i = 0; i < 10; ++i)
                    b[i] = *reinterpret_cast<const float4*>(up + 960 + 4 * i);
#pragma unroll
                for (int i = 10; i < 16; ++i)
                    b[i] = make_float4(0.f, 0.f, 0.f, 0.f);
            }
        };

        // 4 LIF steps; spike bits -> bw at (sh..sh+3); returns v float4
        auto step4 = [&](const float4 u4, unsigned& bw, int sh) -> float4 {
            const float uin[4] = {u4.x, u4.y, u4.z, u4.w};
            float vo[4];
#pragma unroll
            for (int k = 0; k < 4; ++k) {
                // u_eff = u_t * (1 - (ref>0))
                const float ueff = (ref > 0.0f) ? 0.0f : uin[k];
                // v = 0.95*v + u_eff   (separate mul/add, no FMA)
                v = __fadd_rn(__fmul_rn(0.95f, v), ueff);
                // s = (v - theta >= 0)
                const float d = __fsub_rn(v, theta);
                const bool s = (d >= 0.0f);
                // v -= s*theta
                v = s ? __fsub_rn(v, theta) : v;
                // ref = max(ref-1,0); if (s) ref = 2
                ref = fmaxf(__fsub_rn(ref, 1.0f), 0.0f);
                ref = s ? 2.0f : ref;
                // theta = theta*0.995 + tb*0.005 + 0.35*s
                theta = __fadd_rn(__fmul_rn(theta, 0.995f), c5);
                theta = s ? __fadd_rn(theta, 0.35f) : theta;

                bw |= (s ? 1u : 0u) << (sh + k);   // off the serial chain
                vo[k] = v;
            }
            return make_float4(vo[0], vo[1], vo[2], vo[3]);
        };

        // one 64-step group: slot0 = phase-local f4 base (0,16,32,48)
        auto proc_g = [&](const float4 (&b)[16], int slot0, int pb, int g) {
            unsigned blo = 0, bhi = 0;
#pragma unroll
            for (int tf = 0; tf < 16; ++tf) {
                float4 v4 = step4(b[tf], (tf < 8) ? blo : bhi, 4 * (tf & 7));
                *reinterpret_cast<float4*>(&v_lds[lane][4 * (slot0 + tf)]) = v4;
            }
            *reinterpret_cast<uint2*>(&s_bits[pb][lane][2 * g]) =
                make_uint2(blo, bhi);
        };

        load_g(bufA, 0);
#pragma unroll 1
        for (int p = 0; p < NPH; ++p) {
            const int g0 = 4 * p;
            const int pb = p & 1;
            load_g(bufB, g0 + 1);
            proc_g(bufA, 0, pb, 0);
            load_g(bufA, g0 + 2);
            proc_g(bufB, 16, pb, 1);
            load_g(bufB, g0 + 3);
            proc_g(bufA, 32, pb, 2);
            if (p < 3) load_g(bufA, g0 + 4);
            proc_g(bufB, 48, pb, 3);
            LGKM0();
            WAVE_BARRIER();            // B1: phase data ready
            WAVE_BARRIER();            // B2: storers consumed v_lds
        }
    } else if (wid <= 2) {
        // ---------------- v-storer waves (rows 32w .. 32w+31) ----------------
        float* gv = vhist + (size_t)blk0 * T_;
        const int rbase = 32 * (wid - 1);
        float4 st[32];                 // register stage (static indexing)

#pragma unroll 1
        for (int p = 0; p < NPH; ++p) {
            WAVE_BARRIER();            // B1
#pragma unroll
            for (int i = 0; i < 32; ++i)
                st[i] = *reinterpret_cast<const float4*>(
                    &v_lds[rbase + i][4 * lane]);
            LGKM0();
            WAVE_BARRIER();            // B2: buffer free
            const int t0 = QSTEP * p;
            if (lane < ((p == 3) ? 58 : 64)) {
#pragma unroll
                for (int i = 0; i < 32; ++i)
                    *reinterpret_cast<float4*>(
                        gv + (size_t)(rbase + i) * T_ + t0 + 4 * lane) = st[i];
            }
        }
    } else {
        // ---------------- s-storer (expand bits -> 0.0f/1.0f) ----------------
        float* gs = spikes + (size_t)blk0 * T_;
        const int wq = lane >> 3;          // u32 word within row (0..7)
        const int ob = 4 * (lane & 7);     // bit offset within word

#pragma unroll 1
        for (int p = 0; p < NPH; ++p) {
            WAVE_BARRIER();            // B1
            WAVE_BARRIER();            // B2 (no v_lds hold: bits are dbuf'd)
            const int t0 = QSTEP * p;
            const int pb = p & 1;
            if (lane < ((p == 3) ? 58 : 64)) {
#pragma unroll
                for (int r = 0; r < 64; ++r) {
                    const unsigned wb = s_bits[pb][r][wq];
                    float4 f;
                    f.x = ((wb >> (ob + 0)) & 1u) ? 1.0f : 0.0f;
                    f.y = ((wb >> (ob + 1)) & 1u) ? 1.0f : 0.0f;
                    f.z = ((wb >> (ob + 2)) & 1u) ? 1.0f : 0.0f;
                    f.w = ((wb >> (ob + 3)) & 1u) ? 1.0f : 0.0f;
                    *reinterpret_cast<float4*>(
                        gs + (size_t)r * T_ + t0 + 4 * lane) = f;
                }
            }
        }
    }
}

extern "C" void kernel_launch(void* const* d_in, const int* in_sizes, int n_in,
                              void* d_out, int out_size, void* d_ws, size_t ws_size,
                              hipStream_t stream) {
    const float* u = (const float*)d_in[0];           // (B,N,T)
    const float* theta_base = (const float*)d_in[1];  // (1,N,1)
    float* out = (float*)d_out;
    float* spikes = out;                               // first output
    float* vhist = out + (size_t)B_ * N_ * T_;         // second output

    const int grid = (B_ * N_) / 64;   // 512 blocks (64 neurons each)
    lif_kernel<<<grid, 256, 0, stream>>>(u, theta_base, spikes, vhist);
}

// Round 10
// 122.430 us; speedup vs baseline: 1.2697x; 1.2697x over previous
//
#include <hip/hip_runtime.h>

// LIF neuron bank: B=16, N=2048, T=1000.
//
// R10 = R8 with the lif_expand GRID FIXED (was 2048 blocks = half the rows;
// spikes rows >=16384 never written -> absmax 1.0).
//
// K1 (512 blocks x 192): 16 phases of 64 steps, single barrier/phase.
//   w0 compute: reads u from LDS ring (16x ds_read_b128, swizzled), runs the
//     serial chain, writes v to LDS dbuf (swizzled) and 64-step spike
//     BITMASKS (uint64/lane = 512B/wave contiguous) straight to d_ws.
//   w1 loader: global_load_lds dwordx4; inst k = rows 4k..4k+3 x 256B
//     contiguous; global source pre-swizzled (slot = sl ^ (r&15)) so the
//     linear LDS dest yields conflict-lite compute reads. 3-deep ring ->
//     2 chunks (32 insts, ~512 lines/CU) always in flight; counted
//     s_waitcnt vmcnt(16), never drains stores (it has none).
//   w2 v-storer: R4's proven 256B-per-row store pattern, one phase behind.
// LDS: u ring 48KB + v dbuf 32KB = 80KB -> 2 blocks/CU.
// K2 (4096 blocks x 256): expands spike bits -> exact 1.0f/0.0f; each wave
// writes 2 whole rows (4KB contiguous per row-half). Pure streaming stores.
//
// FP discipline: reference does NOT contract mul+add into FMA; use
// __fmul_rn/__fadd_rn/__fsub_rn to stay bit-exact (R0-R7: absmax 0.0).

constexpr int B_ = 16;
constexpr int N_ = 2048;
constexpr int T_ = 1000;
constexpr int CH = 64;                 // steps per chunk
constexpr int NCH = 16;                // chunks; last has 40 valid steps
constexpr long NEUR = (long)B_ * N_;   // 32768

#define LGKM0()                                                \
    do {                                                       \
        asm volatile("s_waitcnt lgkmcnt(0)" ::: "memory");     \
        __builtin_amdgcn_sched_barrier(0);                     \
    } while (0)

__device__ __forceinline__ void gload_lds16(const float* g, void* lds) {
    __builtin_amdgcn_global_load_lds(
        (const __attribute__((address_space(1))) void*)g,
        (__attribute__((address_space(3))) void*)lds, 16, 0, 0);
}

__global__ __launch_bounds__(192) void lif_pass1(
    const float* __restrict__ u,           // (B, N, T)
    const float* __restrict__ theta_base,  // N floats
    float* __restrict__ vhist,             // (B, N, T)
    unsigned long long* __restrict__ wsbits) // [chunk][neuron] spike bits
{
    __shared__ float4 u_ring[3][64][16];   // 48 KiB
    __shared__ float4 v_lds[2][64][16];    // 32 KiB

    const int lane = threadIdx.x & 63;
    const int wid = threadIdx.x >> 6;
    const int blk0 = blockIdx.x * 64;

    if (wid == 1) {
        // ---------------- loader wave ----------------
        const float* ub = u + (size_t)blk0 * T_;
        const int rs = lane >> 4;      // row-sub within 4-row group
        const int sl = lane & 15;      // phys slot this lane fills

        auto issue = [&](int c) {
            const int bq = c % 3;
            if (c < 15) {
                const int t0 = c * CH;
#pragma unroll
                for (int k = 0; k < 16; ++k) {
                    const int r = 4 * k + rs;
                    // pre-swizzled global source; LDS dest linear (1KB/inst)
                    const float* g =
                        ub + (size_t)r * T_ + t0 + 4 * (sl ^ (r & 15));
                    gload_lds16(g, &u_ring[bq][4 * k][0]);
                }
            } else {
                // tail chunk: logical tf = sl ^ (r&15); only tf<10 valid
#pragma unroll
                for (int k = 0; k < 16; ++k) {
                    const int r = 4 * k + rs;
                    const int tf = sl ^ (r & 15);
                    if (tf < 10) {
                        const float* g = ub + (size_t)r * T_ + 960 + 4 * tf;
                        gload_lds16(g, &u_ring[bq][4 * k][0]);
                    }
                }
            }
        };

        issue(0);
        issue(1);
        asm volatile("s_waitcnt vmcnt(16)" ::: "memory");  // chunk 0 landed
        __builtin_amdgcn_sched_barrier(0);
        __builtin_amdgcn_s_barrier();                      // B(-1)
#pragma unroll 1
        for (int c = 0; c < NCH; ++c) {
            if (c + 2 < NCH) {
                issue(c + 2);          // into buf (c+2)%3 == (c-1)%3 (freed)
                asm volatile("s_waitcnt vmcnt(16)" ::: "memory"); // c+1 landed
            } else {
                asm volatile("s_waitcnt vmcnt(0)" ::: "memory");
            }
            __builtin_amdgcn_sched_barrier(0);
            __builtin_amdgcn_s_barrier();
            __builtin_amdgcn_sched_barrier(0);
        }
    } else if (wid == 0) {
        // ---------------- compute wave ----------------
        const float tb = theta_base[(blk0 + lane) & (N_ - 1)];
        const float c5 = __fmul_rn(tb, 0.005f);   // tb * (1-0.995) rounded
        float v = 0.0f, theta = tb, ref = 0.0f;
        const int sw = lane & 15;

        __builtin_amdgcn_s_barrier();              // B(-1)
#pragma unroll 1
        for (int c = 0; c < NCH; ++c) {
            const int bq = c % 3;
            const int pb = c & 1;
            // pull the whole chunk into registers (static indexing)
            float4 ubuf[16];
#pragma unroll
            for (int tf = 0; tf < 16; ++tf)
                ubuf[tf] = u_ring[bq][lane][tf ^ sw];
            // (tail: slots with logical tf>=10 hold stale data -> feeds dead
            //  steps 40..63 of the last chunk; their outputs are never stored)
            unsigned blo = 0, bhi = 0;
#pragma unroll
            for (int tf = 0; tf < 16; ++tf) {
                const float uin[4] = {ubuf[tf].x, ubuf[tf].y,
                                      ubuf[tf].z, ubuf[tf].w};
                float vo[4];
#pragma unroll
                for (int k = 0; k < 4; ++k) {
                    // u_eff = u_t * (1 - (ref>0))
                    const float ueff = (ref > 0.0f) ? 0.0f : uin[k];
                    // v = 0.95*v + u_eff   (separate mul/add, no FMA)
                    v = __fadd_rn(__fmul_rn(0.95f, v), ueff);
                    // s = (v - theta >= 0)
                    const float d = __fsub_rn(v, theta);
                    const bool s = (d >= 0.0f);
                    // v -= s*theta
                    v = s ? __fsub_rn(v, theta) : v;
                    // ref = max(ref-1,0); if (s) ref = 2
                    ref = fmaxf(__fsub_rn(ref, 1.0f), 0.0f);
                    ref = s ? 2.0f : ref;
                    // theta = theta*0.995 + tb*0.005 + 0.35*s
                    theta = __fadd_rn(__fmul_rn(theta, 0.995f), c5);
                    theta = s ? __fadd_rn(theta, 0.35f) : theta;

                    if (tf < 8) blo |= (s ? 1u : 0u) << (4 * tf + k);
                    else        bhi |= (s ? 1u : 0u) << (4 * (tf - 8) + k);
                    vo[k] = v;
                }
                v_lds[pb][lane][tf ^ sw] =
                    make_float4(vo[0], vo[1], vo[2], vo[3]);
            }
            // spike bits -> workspace: 512B contiguous per wave per chunk
            wsbits[(size_t)c * NEUR + blk0 + lane] =
                ((unsigned long long)bhi << 32) | blo;
            LGKM0();
            __builtin_amdgcn_s_barrier();
        }
    } else {
        // ---------------- v-storer wave ----------------
        float* gv = vhist + (size_t)blk0 * T_;
        const int rs = lane >> 4;
        const int sl = lane & 15;

        __builtin_amdgcn_s_barrier();              // B(-1)
#pragma unroll 1
        for (int c = 0; c < NCH; ++c) {
            if (c >= 1) {
                const int pc = c - 1;
                const int pb = pc & 1;
                const int t0 = pc * CH;
#pragma unroll
                for (int k = 0; k < 16; ++k) {
                    const int r = 4 * k + rs;
                    const float4 w = v_lds[pb][r][sl ^ (r & 15)];
                    *(float4*)(gv + (size_t)r * T_ + t0 + 4 * sl) = w;
                }
            }
            LGKM0();
            __builtin_amdgcn_s_barrier();
        }
        // epilogue: tail chunk (c=15, pb=1): 10 valid float4 per row
#pragma unroll
        for (int k = 0; k < 16; ++k) {
            const int r = 4 * k + rs;
            if (sl < 10) {
                const float4 w = v_lds[1][r][sl ^ (r & 15)];
                *(float4*)(gv + (size_t)r * T_ + 960 + 4 * sl) = w;
            }
        }
    }
}

__global__ __launch_bounds__(256) void lif_expand(
    const unsigned* __restrict__ wsbits,  // u32 view: [chunk][neuron][2]
    float* __restrict__ spikes)           // (B, N, T)
{
    const int tid = blockIdx.x * 256 + threadIdx.x;
    const int lane = tid & 63;
    const long wavei = tid >> 6;              // 0..16383
    const long row = 2 * wavei + (lane >> 5); // 2 adjacent rows per wave
    const int k = lane & 31;                  // 2*chunk + half
    const int c = k >> 1;
    const int half = k & 1;

    const unsigned w = wsbits[(((size_t)c * NEUR + row) << 1) | half];
    const int t0 = 64 * c + 32 * half;
    float* gp = spikes + (size_t)row * T_ + t0;

#pragma unroll
    for (int j = 0; j < 8; ++j) {
        if (t0 + 4 * j < T_) {                // only the last half trims (j<2)
            float4 f;
            f.x = ((w >> (4 * j + 0)) & 1u) ? 1.0f : 0.0f;
            f.y = ((w >> (4 * j + 1)) & 1u) ? 1.0f : 0.0f;
            f.z = ((w >> (4 * j + 2)) & 1u) ? 1.0f : 0.0f;
            f.w = ((w >> (4 * j + 3)) & 1u) ? 1.0f : 0.0f;
            *(float4*)(gp + 4 * j) = f;
        }
    }
}

extern "C" void kernel_launch(void* const* d_in, const int* in_sizes, int n_in,
                              void* d_out, int out_size, void* d_ws, size_t ws_size,
                              hipStream_t stream) {
    const float* u = (const float*)d_in[0];           // (B,N,T)
    const float* theta_base = (const float*)d_in[1];  // (1,N,1)
    float* out = (float*)d_out;
    float* spikes = out;                               // first output
    float* vhist = out + (size_t)B_ * N_ * T_;         // second output
    unsigned long long* wsbits = (unsigned long long*)d_ws;  // 4 MiB used

    lif_pass1<<<NEUR / 64, 192, 0, stream>>>(u, theta_base, vhist, wsbits);
    // one wave per 2 rows: NEUR/2 waves = NEUR*64/2 threads -> NEUR/8 blocks
    lif_expand<<<NEUR / 8, 256, 0, stream>>>((const unsigned*)wsbits, spikes);
}